// Round 4
// baseline (183.368 us; speedup 1.0000x reference)
//
#include <hip/hip_runtime.h>

typedef _Float16 f16x8 __attribute__((ext_vector_type(8)));
typedef _Float16 f16x2 __attribute__((ext_vector_type(2)));
typedef float    f32x4 __attribute__((ext_vector_type(4)));
typedef float    f32x16 __attribute__((ext_vector_type(16)));

#define N_CTX 16384
#define N_Q   4096
#define DIM   100
#define THR   4.0f

union PkU   { f16x2 h2; unsigned int u; };
union FragU { unsigned int u[4]; f16x8 v; };

static __device__ __forceinline__ unsigned short f2h_bits(float f) {
    union { _Float16 h; unsigned short u; } v;
    v.h = (_Float16)f;
    return v.u;
}

#define MFMA32(a, b, c) __builtin_amdgcn_mfma_f32_32x32x16_f16((a), (b), (c), 0, 0, 0)

// ---------------- fused prep ----------------
// blocks 0..15   : qb rows (q fp16, elem 100 = t_j, rest 0)
// blocks 16..79  : a
// blocks 80..143 : qT transpose (rows 100..127 zeroed)
__global__ void prep_all(const float* __restrict__ q, const float* __restrict__ ctx,
                         const float* __restrict__ ker,
                         unsigned short* __restrict__ qb, unsigned short* __restrict__ qT,
                         float* __restrict__ a) {
    int b = blockIdx.x;
    int tid = threadIdx.x;
    if (b < 16) {
        int j = b * 256 + tid;
        const float* row = q + (size_t)j * DIM;
        float buf[100];
        float acc = 0.f;
        #pragma unroll
        for (int d4 = 0; d4 < 25; ++d4) {
            f32x4 v = *reinterpret_cast<const f32x4*>(row + 4 * d4);
            #pragma unroll
            for (int e = 0; e < 4; ++e) {
                buf[4 * d4 + e] = v[e];
                acc += v[e] * ker[100 + 4 * d4 + e];
            }
        }
        unsigned short* orow = qb + (size_t)j * 128;
        #pragma unroll
        for (int c = 0; c < 16; ++c) {
            f16x8 h;
            #pragma unroll
            for (int e = 0; e < 8; ++e) {
                int d = 8 * c + e;
                float v = (d < DIM) ? buf[d] : (d == DIM ? acc : 0.f);
                h[e] = (_Float16)v;
            }
            *reinterpret_cast<f16x8*>(orow + 8 * c) = h;
        }
    } else if (b < 80) {
        int i = (b - 16) * 256 + tid;
        const float* row = ctx + (size_t)i * DIM;
        float acc = 0.f;
        #pragma unroll
        for (int d4 = 0; d4 < 25; ++d4) {
            f32x4 v = *reinterpret_cast<const f32x4*>(row + 4 * d4);
            acc += v[0] * ker[4 * d4] + v[1] * ker[4 * d4 + 1]
                 + v[2] * ker[4 * d4 + 2] + v[3] * ker[4 * d4 + 3];
        }
        a[i] = acc;
    } else {
        __shared__ _Float16 ldsT[100][64];
        int j0 = (b - 80) * 64;
        int r = tid >> 2, c = tid & 3;
        const float* row = q + (size_t)(j0 + r) * DIM + c * 25;
        #pragma unroll
        for (int k = 0; k < 25; ++k) ldsT[c * 25 + k][r] = (_Float16)row[k];
        __syncthreads();
        for (int idx = tid; idx < 128 * 64; idx += 256) {
            int d = idx >> 6, jj = idx & 63;
            qT[(size_t)d * N_Q + j0 + jj] = (d < DIM) ? *(unsigned short*)&ldsT[d][jj]
                                                      : (unsigned short)0;
        }
    }
}

// ---------------- main fused attention ----------------
// 512 blocks x 256 thr (4 waves). Block rows [i0,i0+32); wave w sweeps
// j in [w*1024,(w+1)*1024) by 32. Depth-2 aq prefetch; t folded at k=100.
__global__ __launch_bounds__(256, 2) void attn_main(
    const unsigned short* __restrict__ qb, const unsigned short* __restrict__ qT,
    const float* __restrict__ a, const float* __restrict__ ctx,
    const float* __restrict__ ker,
    float* __restrict__ G, float* __restrict__ mfull)
{
    __shared__ _Float16 cbL[32 * 128];
    __shared__ float smU[4][100][32];
    __shared__ float smM[4][32], smL[4][32], smMt[4][32];

    const int tid  = threadIdx.x;
    const int w    = tid >> 6;
    const int lane = tid & 63;
    const int hi   = lane >> 5;
    const int c31  = lane & 31;
    const int i0   = blockIdx.x * 32;

    // stage cb tile: fp16(ctx*w3), elem 100 = 1.0 (bias column), XOR-swizzled
    {
        int i  = tid >> 3;              // 0..31
        int d0 = (tid & 7) * 16;        // 0..112
        const float* crow = ctx + (size_t)(i0 + i) * DIM;
        f16x8 v0, v1;
        #pragma unroll
        for (int e = 0; e < 8; ++e) {
            int d = d0 + e;
            v0[e] = (d < DIM) ? (_Float16)(crow[d] * ker[200 + d])
                              : (d == DIM ? (_Float16)1.f : (_Float16)0.f);
        }
        #pragma unroll
        for (int e = 0; e < 8; ++e) {
            int d = d0 + 8 + e;
            v1[e] = (d < DIM) ? (_Float16)(crow[d] * ker[200 + d])
                              : (d == DIM ? (_Float16)1.f : (_Float16)0.f);
        }
        int base = i * 256 + d0 * 2;
        int swz  = (i & 7) << 4;
        *reinterpret_cast<f16x8*>(reinterpret_cast<char*>(cbL) + ((base) ^ swz))      = v0;
        *reinterpret_cast<f16x8*>(reinterpret_cast<char*>(cbL) + ((base + 16) ^ swz)) = v1;
    }
    __syncthreads();

    // persistent cb B-fragments (28 VGPR)
    f16x8 cbF[7];
    {
        int cswz = (c31 & 7) << 4;
        #pragma unroll
        for (int kk = 0; kk < 7; ++kk)
            cbF[kk] = *reinterpret_cast<const f16x8*>(
                reinterpret_cast<const char*>(cbL) + ((c31 * 256 + kk * 32 + hi * 16) ^ cswz));
    }

    f32x16 U0 = {}, U1 = {}, U2 = {}, U3 = {};
    float m = -INFINITY, mtrue = -INFINITY, l = 0.f;

    const unsigned short* qrow = qb + (size_t)(w * 1024 + c31) * 128 + 8 * hi;
    const unsigned short* vrow = qT + (size_t)c31 * N_Q + w * 1024 + 8 * hi;

    auto compute = [&](const f16x8* aq, const unsigned short* vr) {
        // QK^T (t folded at k=100)
        f32x16 sa = {}, sb = {};
        __builtin_amdgcn_s_setprio(1);
        sa = MFMA32(aq[0], cbF[0], sa);
        sb = MFMA32(aq[1], cbF[1], sb);
        sa = MFMA32(aq[2], cbF[2], sa);
        sb = MFMA32(aq[3], cbF[3], sb);
        sa = MFMA32(aq[4], cbF[4], sa);
        sb = MFMA32(aq[5], cbF[5], sb);
        sa = MFMA32(aq[6], cbF[6], sa);
        __builtin_amdgcn_s_setprio(0);

        // V loads — issued early, consumed ~600cy later at PV
        f16x8 av0 = *reinterpret_cast<const f16x8*>(vr);
        f16x8 av1 = *reinterpret_cast<const f16x8*>(vr + 16);
        f16x8 av2 = *reinterpret_cast<const f16x8*>(vr + 32 * N_Q);
        f16x8 av3 = *reinterpret_cast<const f16x8*>(vr + 32 * N_Q + 16);
        f16x8 av4 = *reinterpret_cast<const f16x8*>(vr + 64 * N_Q);
        f16x8 av5 = *reinterpret_cast<const f16x8*>(vr + 64 * N_Q + 16);
        f16x8 av6 = *reinterpret_cast<const f16x8*>(vr + 96 * N_Q);
        f16x8 av7 = *reinterpret_cast<const f16x8*>(vr + 96 * N_Q + 16);

        float sc[16];
        #pragma unroll
        for (int r = 0; r < 16; ++r) sc[r] = sa[r] + sb[r];

        // per-half tile max (no cross-half shfl on steady-state path)
        float t0 = fmaxf(sc[0], sc[1]),  t1 = fmaxf(sc[2], sc[3]);
        float t2 = fmaxf(sc[4], sc[5]),  t3 = fmaxf(sc[6], sc[7]);
        float t4 = fmaxf(sc[8], sc[9]),  t5 = fmaxf(sc[10], sc[11]);
        float t6 = fmaxf(sc[12], sc[13]), t7 = fmaxf(sc[14], sc[15]);
        t0 = fmaxf(t0, t1); t2 = fmaxf(t2, t3); t4 = fmaxf(t4, t5); t6 = fmaxf(t6, t7);
        float tm = fmaxf(fmaxf(t0, t2), fmaxf(t4, t6));
        mtrue = fmaxf(mtrue, tm);

        if (__any(tm > m + THR)) {
            float tmf = fmaxf(tm, __shfl_xor(tm, 32, 64));
            float mn = fmaxf(m, tmf);
            float scale = __expf(m - mn);
            U0 *= scale; U1 *= scale; U2 *= scale; U3 *= scale;
            l *= scale;
            m = mn;
        }

        float ps = 0.f;
        #pragma unroll
        for (int r = 0; r < 16; ++r) { sc[r] = __expf(sc[r] - m); ps += sc[r]; }
        l += ps;

        // P -> PV B-operand
        unsigned int pk[8], pr[8];
        #pragma unroll
        for (int h2 = 0; h2 < 8; ++h2) {
            PkU u; u.h2[0] = (_Float16)sc[2 * h2]; u.h2[1] = (_Float16)sc[2 * h2 + 1];
            pk[h2] = u.u;
            pr[h2] = (unsigned int)__shfl_xor((int)pk[h2], 32, 64);
        }
        FragU f0, f1;
        f0.u[0] = hi ? pr[2] : pk[0];
        f0.u[1] = hi ? pr[3] : pk[1];
        f0.u[2] = hi ? pk[2] : pr[0];
        f0.u[3] = hi ? pk[3] : pr[1];
        f1.u[0] = hi ? pr[6] : pk[4];
        f1.u[1] = hi ? pr[7] : pk[5];
        f1.u[2] = hi ? pk[6] : pr[4];
        f1.u[3] = hi ? pk[7] : pr[5];

        __builtin_amdgcn_s_setprio(1);
        U0 = MFMA32(av0, f0.v, U0);
        U1 = MFMA32(av2, f0.v, U1);
        U2 = MFMA32(av4, f0.v, U2);
        U3 = MFMA32(av6, f0.v, U3);
        U0 = MFMA32(av1, f1.v, U0);
        U1 = MFMA32(av3, f1.v, U1);
        U2 = MFMA32(av5, f1.v, U2);
        U3 = MFMA32(av7, f1.v, U3);
        __builtin_amdgcn_s_setprio(0);
    };

    // depth-2 software pipeline on the aq operand
    f16x8 aqA[7], aqB[7];
    #pragma unroll
    for (int kk = 0; kk < 7; ++kk)
        aqA[kk] = *reinterpret_cast<const f16x8*>(qrow + kk * 16);

    for (int s = 0; s < 32; s += 2) {
        const unsigned short* qn = qrow + 4096;      // step s+1 rows
        #pragma unroll
        for (int kk = 0; kk < 7; ++kk)
            aqB[kk] = *reinterpret_cast<const f16x8*>(qn + kk * 16);
        compute(aqA, vrow);
        vrow += 32;

        qrow += 8192;                                 // step s+2 rows
        #pragma unroll
        for (int kk = 0; kk < 7; ++kk)
            aqA[kk] = *reinterpret_cast<const f16x8*>(qrow + kk * 16);
        compute(aqB, vrow);
        vrow += 32;
    }

    // cross-half finalize
    l += __shfl_xor(l, 32, 64);
    mtrue = fmaxf(mtrue, __shfl_xor(mtrue, 32, 64));

    // stash per-wave partials (f32)
    #pragma unroll
    for (int r = 0; r < 16; ++r) {
        int dl = (r & 3) + 8 * (r >> 2) + 4 * hi;
        smU[w][dl][c31]      = U0[r];
        smU[w][32 + dl][c31] = U1[r];
        smU[w][64 + dl][c31] = U2[r];
        if (96 + dl < DIM) smU[w][96 + dl][c31] = U3[r];
    }
    if (lane < 32) { smM[w][c31] = m; smL[w][c31] = l; smMt[w][c31] = mtrue; }
    __syncthreads();

    // split-K combine + epilogue (G cols 0..299, mfull)
    {
        int i32 = tid & 31;
        int seg = tid >> 5;                  // 0..7
        float M = -INFINITY;
        #pragma unroll
        for (int ww = 0; ww < 4; ++ww) M = fmaxf(M, smM[ww][i32]);
        float ew[4];
        float L = 0.f, Mt = -INFINITY;
        #pragma unroll
        for (int ww = 0; ww < 4; ++ww) {
            ew[ww] = __expf(smM[ww][i32] - M);
            L += smL[ww][i32] * ew[ww];
            Mt = fmaxf(Mt, smMt[ww][i32]);
        }
        int row = i0 + i32;
        if (seg == 0) mfull[row] = a[row] + Mt;
        float invL = 1.f / L;
        for (int d = seg; d < DIM; d += 8) {
            float u = 0.f;
            #pragma unroll
            for (int ww = 0; ww < 4; ++ww) u += smU[ww][d][i32] * ew[ww];
            float ua = u * invL;
            float cv = ctx[(size_t)row * DIM + d];
            size_t base = (size_t)row * 400;
            G[base + d]       = cv;
            G[base + 100 + d] = ua;
            G[base + 200 + d] = ua * cv;
        }
    }
}

// ---------------- b-softmax + h ----------------
__global__ void kernel_h(const float* __restrict__ mfull, const float* __restrict__ ctx,
                         float* __restrict__ hp) {
    __shared__ float sm[256];
    int t = threadIdx.x;
    float v = -INFINITY;
    for (int i = t; i < N_CTX; i += 256) v = fmaxf(v, mfull[i]);
    sm[t] = v; __syncthreads();
    for (int s = 128; s > 0; s >>= 1) { if (t < s) sm[t] = fmaxf(sm[t], sm[t + s]); __syncthreads(); }
    float M = sm[0];
    __syncthreads();
    float z = 0.f;
    for (int i = t; i < N_CTX; i += 256) z += __expf(mfull[i] - M);
    sm[t] = z; __syncthreads();
    for (int s = 128; s > 0; s >>= 1) { if (t < s) sm[t] += sm[t + s]; __syncthreads(); }
    float Z = sm[0];
    if (t < DIM) {
        int i0 = blockIdx.x * 64;
        float acc = 0.f;
        for (int r = 0; r < 64; ++r)
            acc += __expf(mfull[i0 + r] - M) * ctx[(size_t)(i0 + r) * DIM + t];
        hp[t * 256 + blockIdx.x] = acc / Z;
    }
}

__global__ void kernel_hred(const float* __restrict__ hp, float* __restrict__ h) {
    __shared__ float sm[4][128];
    int t = threadIdx.x;
    int d = t & 127, rep = t >> 7;
    float s = 0.f;
    if (d < DIM) for (int b = 0; b < 64; ++b) s += hp[d * 256 + rep * 64 + b];
    sm[rep][d] = s;
    __syncthreads();
    if (rep == 0 && d < DIM) h[d] = sm[0][d] + sm[1][d] + sm[2][d] + sm[3][d];
}

__global__ void kernel_g4(const float* __restrict__ ctx, const float* __restrict__ h,
                          float* __restrict__ G) {
    int idx = blockIdx.x * 256 + threadIdx.x;
    if (idx >= N_CTX * DIM) return;
    int i = idx / DIM;
    int d = idx - i * DIM;
    G[(size_t)i * 400 + 300 + d] = ctx[idx] * h[d];
}

// ---------------- launcher ----------------
extern "C" void kernel_launch(void* const* d_in, const int* in_sizes, int n_in,
                              void* d_out, int out_size, void* d_ws, size_t ws_size,
                              hipStream_t stream) {
    const float* ctx = (const float*)d_in[0];
    const float* q   = (const float*)d_in[1];
    const float* ker = (const float*)d_in[2];
    float* G = (float*)d_out;

    char* ws = (char*)d_ws;
    unsigned short* qb    = (unsigned short*)(ws);                 // 1,048,576
    unsigned short* qT    = (unsigned short*)(ws + 1048576);       // 1,048,576
    float*          a     = (float*)(ws + 2097152);                // 65,536
    float*          mfull = (float*)(ws + 2162688);                // 65,536
    float*          hp    = (float*)(ws + 2228224);                // 102,400
    float*          h     = (float*)(ws + 2330624);                // 400

    prep_all<<<dim3(144), dim3(256), 0, stream>>>(q, ctx, ker, qb, qT, a);
    attn_main<<<dim3(512), dim3(256), 0, stream>>>(qb, qT, a, ctx, ker, G, mfull);
    kernel_h<<<dim3(256), dim3(256), 0, stream>>>(mfull, ctx, hp);
    kernel_hred<<<dim3(1), dim3(512), 0, stream>>>(hp, h);
    kernel_g4<<<dim3(6400), dim3(256), 0, stream>>>(ctx, h, G);
}